// Round 7
// baseline (253.670 us; speedup 1.0000x reference)
//
#include <hip/hip_runtime.h>

// Efficient (linear) attention, fused MFMA implementation for gfx950.  v4-r6
// B=4, NX=NY=16384, C=256, H=8, dk=dv=32.  M = B*N = 65536 rows.
// R2 change: kv_kernel -> zero-LDS register-streaming form. A-frags built in
// VGPRs straight from global fp32 (no staging, no barriers, no bank conflicts);
// B streamed 8-frags-per-nf with only 8 live acc regs so loads can pipeline.

typedef float f32x4 __attribute__((ext_vector_type(4)));
typedef short s16x4 __attribute__((ext_vector_type(4)));
typedef short s16x8 __attribute__((ext_vector_type(8)));

#define MFMA16(A, B, C) __builtin_amdgcn_mfma_f32_16x16x32_bf16((A), (B), (C), 0, 0, 0)

__device__ __forceinline__ short f2bf(float f) {
    unsigned u = __builtin_bit_cast(unsigned, f);
    u = (u + 0x7FFFu + ((u >> 16) & 1u)) >> 16;   // RNE
    return (short)u;
}
__device__ __forceinline__ float bf2f(short b) {
    unsigned u = ((unsigned)(unsigned short)b) << 16;
    return __builtin_bit_cast(float, u);
}

// ---------------------------------------------------------------------------
// K0: convert the 4 weight matrices (each 256x256 fp32, [n][c] row-major) to bf16
// ---------------------------------------------------------------------------
__global__ __launch_bounds__(256) void wcvt_kernel(
    const float* __restrict__ wq, const float* __restrict__ wk,
    const float* __restrict__ wv, const float* __restrict__ wr,
    short* __restrict__ wbf)
{
    int i = blockIdx.x * 256 + threadIdx.x;      // 65536 threads, 4 elems each
    int m = i >> 14;                             // matrix id (uniform per block)
    int off = (i & 16383) * 4;
    const float* src = (m == 0) ? wq : (m == 1) ? wk : (m == 2) ? wv : wr;
    f32x4 v = *(const f32x4*)(src + off);
    s16x4 o;
    o[0] = f2bf(v[0]); o[1] = f2bf(v[1]); o[2] = f2bf(v[2]); o[3] = f2bf(v[3]);
    *(s16x4*)(wbf + (size_t)m * 65536 + off) = o;
}

// ---------------------------------------------------------------------------
// K1: e = exp((y+ypos) @ Wk^T + bk), v = y @ Wv^T + bv   -> bf16 buffers
// Zero-LDS form. block: 256 thr (4 waves), 32-row tile, grid 2048.
// wave w: is_k = (w<2), colbase = (w&1)*128 -> 32 rows x 128 cols per wave.
// A-frags af[mf][ks] live in VGPRs (lane: row=mf*16+lrow, k=ks*32+lgrp*8..+8).
// Per nf: stream 8 B-frags, 16 MFMAs into 2 f32x4 accs, store immediately.
// ---------------------------------------------------------------------------
__global__ __launch_bounds__(256, 3) void kv_kernel(
    const float* __restrict__ y, const float* __restrict__ ypos,
    const short* __restrict__ wk_bf, const short* __restrict__ wv_bf,
    const float* __restrict__ bk, const float* __restrict__ bv,
    short* __restrict__ e_buf, short* __restrict__ v_buf)
{
    const int row0 = blockIdx.x * 32;
    const int t = threadIdx.x;
    const int w = t >> 6, lane = t & 63;
    const int lrow = lane & 15, lgrp = lane >> 4;
    const bool is_k = (w < 2);                   // wave-uniform
    const int colbase = (w & 1) * 128;
    const short* WB = is_k ? wk_bf : wv_bf;
    const float* bp = is_k ? bk : bv;
    short* obuf = is_k ? e_buf : v_buf;

    // Build A fragments in registers straight from global fp32.
    s16x8 af[2][8];
    #pragma unroll
    for (int mf = 0; mf < 2; ++mf) {
        const float* src = y    + (size_t)(row0 + mf * 16 + lrow) * 256 + lgrp * 8;
        const float* ps  = ypos + (size_t)(row0 + mf * 16 + lrow) * 256 + lgrp * 8;
        #pragma unroll
        for (int ks = 0; ks < 8; ++ks) {
            f32x4 a = *(const f32x4*)(src + ks * 32);
            f32x4 b = *(const f32x4*)(src + ks * 32 + 4);
            if (is_k) {
                a += *(const f32x4*)(ps + ks * 32);
                b += *(const f32x4*)(ps + ks * 32 + 4);
            }
            s16x8 o;
            o[0]=f2bf(a[0]); o[1]=f2bf(a[1]); o[2]=f2bf(a[2]); o[3]=f2bf(a[3]);
            o[4]=f2bf(b[0]); o[5]=f2bf(b[1]); o[6]=f2bf(b[2]); o[7]=f2bf(b[3]);
            af[mf][ks] = o;
        }
    }

    #pragma unroll
    for (int nf = 0; nf < 8; ++nf) {
        const int col = colbase + nf * 16 + lrow;
        const short* wrow = WB + (size_t)col * 256 + lgrp * 8;
        s16x8 bf[8];
        #pragma unroll
        for (int ks = 0; ks < 8; ++ks) bf[ks] = *(const s16x8*)(wrow + ks * 32);
        f32x4 a0 = (f32x4){0.f, 0.f, 0.f, 0.f};
        f32x4 a1 = (f32x4){0.f, 0.f, 0.f, 0.f};
        #pragma unroll
        for (int ks = 0; ks < 8; ++ks) {
            a0 = MFMA16(af[0][ks], bf[ks], a0);
            a1 = MFMA16(af[1][ks], bf[ks], a1);
        }
        const float bias = bp[col];
        #pragma unroll
        for (int rr = 0; rr < 4; ++rr) {
            int g0 = row0 + lgrp * 4 + rr;       // rows for mf=0; mf=1 is +16
            float v0 = a0[rr] + bias;
            float v1 = a1[rr] + bias;
            if (is_k) { v0 = __expf(v0); v1 = __expf(v1); }
            obuf[(size_t)g0 * 256 + col]        = f2bf(v0);
            obuf[(size_t)(g0 + 16) * 256 + col] = f2bf(v1);
        }
    }
}

// ---------------------------------------------------------------------------
// K2: ctx partials.  grid (16 chunks, 32 bh).  block 256 thr.
// partial[bh*16+cb][e] : e<1024 -> sum_t exp_k[t][ck]*v[t][cv], e>=1024 -> denom[ck]
// ---------------------------------------------------------------------------
__global__ __launch_bounds__(256) void ctx_kernel(
    const short* __restrict__ e_buf, const short* __restrict__ v_buf,
    float* __restrict__ partials)
{
    __shared__ float se[128 * 32];
    __shared__ float sv[128 * 32];
    __shared__ float red[4 * 1056];
    const int cb = blockIdx.x, bh = blockIdx.y;
    const int b = bh >> 3, h = bh & 7;
    const int tok0 = b * 16384 + cb * 1024;
    const int t = threadIdx.x, w = t >> 6, lane = t & 63;
    const int ckb = (lane >> 3) * 4, cvb = (lane & 7) * 4;

    f32x4 acc[4];
    #pragma unroll
    for (int i = 0; i < 4; ++i) acc[i] = (f32x4){0.f, 0.f, 0.f, 0.f};
    f32x4 dn = (f32x4){0.f, 0.f, 0.f, 0.f};

    for (int it = 0; it < 8; ++it) {
        __syncthreads();
        #pragma unroll
        for (int s = 0; s < 2; ++s) {            // stage 128 tokens x 32 ch
            int id = t + s * 256;
            int rr = id >> 2, pp = id & 3;
            size_t g = (size_t)(tok0 + it * 128 + rr) * 256 + h * 32 + pp * 8;
            s16x8 ee = *(const s16x8*)(e_buf + g);
            s16x8 vv = *(const s16x8*)(v_buf + g);
            f32x4 e0 = {bf2f(ee[0]), bf2f(ee[1]), bf2f(ee[2]), bf2f(ee[3])};
            f32x4 e1 = {bf2f(ee[4]), bf2f(ee[5]), bf2f(ee[6]), bf2f(ee[7])};
            f32x4 v0 = {bf2f(vv[0]), bf2f(vv[1]), bf2f(vv[2]), bf2f(vv[3])};
            f32x4 v1 = {bf2f(vv[4]), bf2f(vv[5]), bf2f(vv[6]), bf2f(vv[7])};
            *(f32x4*)(se + rr * 32 + pp * 8)     = e0;
            *(f32x4*)(se + rr * 32 + pp * 8 + 4) = e1;
            *(f32x4*)(sv + rr * 32 + pp * 8)     = v0;
            *(f32x4*)(sv + rr * 32 + pp * 8 + 4) = v1;
        }
        __syncthreads();
        const int r0 = w * 32;
        #pragma unroll 8
        for (int rr = 0; rr < 32; ++rr) {
            f32x4 e4 = *(const f32x4*)(se + (r0 + rr) * 32 + ckb);
            f32x4 v4 = *(const f32x4*)(sv + (r0 + rr) * 32 + cvb);
            acc[0] += e4[0] * v4;
            acc[1] += e4[1] * v4;
            acc[2] += e4[2] * v4;
            acc[3] += e4[3] * v4;
            dn += e4;
        }
    }
    __syncthreads();
    #pragma unroll
    for (int i = 0; i < 4; ++i)
        *(f32x4*)(red + w * 1056 + (ckb + i) * 32 + cvb) = acc[i];
    if ((lane & 7) == 0)
        *(f32x4*)(red + w * 1056 + 1024 + ckb) = dn;
    __syncthreads();
    float* outp = partials + (size_t)(bh * 16 + cb) * 1056;
    for (int e = t; e < 1056; e += 256)
        outp[e] = red[e] + red[1056 + e] + red[2112 + e] + red[3168 + e];
}

// K2b: reduce 16 chunks, normalize, write ctx^T bf16 [bh][cv][ck]
__global__ __launch_bounds__(256) void ctx_reduce_kernel(
    const float* __restrict__ partials, short* __restrict__ ctxT)
{
    __shared__ float s[1056];
    const int bh = blockIdx.x, t = threadIdx.x;
    for (int e = t; e < 1056; e += 256) {
        float a = 0.f;
        for (int c = 0; c < 16; ++c) a += partials[(size_t)(bh * 16 + c) * 1056 + e];
        s[e] = a;
    }
    __syncthreads();
    for (int e = t; e < 1024; e += 256) {
        int ck = e >> 5, cv = e & 31;
        float val = s[e] / s[1024 + ck];
        ctxT[(size_t)bh * 1024 + cv * 32 + ck] = f2bf(val);
    }
}

// ---------------------------------------------------------------------------
// K3: fused q pass: qpre GEMM -> per-head softmax(32ch) -> attend (ctx^T MFMA)
//     -> LDS -> reproject Wr^T -> fp32 out.   block: 256 thr, 32 rows; grid 2048.
// ---------------------------------------------------------------------------
__global__ __launch_bounds__(256) void qout_kernel(
    const float* __restrict__ x, const float* __restrict__ xpos,
    const short* __restrict__ wq_bf, const float* __restrict__ bq,
    const short* __restrict__ ctxT,
    const short* __restrict__ wr_bf, const float* __restrict__ br,
    float* __restrict__ out)
{
    __shared__ short alds[32 * 256];             // x-tile, then attended (swizzled)
    __shared__ short qlds[4][32 * 64];           // per-wave softmaxed q (swizzled)
    const int row0 = blockIdx.x * 32;
    const int b = row0 >> 14;
    const int t = threadIdx.x;

    { // stage bf16(x+xpos) 32x256
        const int r = t >> 3, p = t & 7;
        const float* s0 = x    + (size_t)(row0 + r) * 256;
        const float* s1 = xpos + (size_t)(row0 + r) * 256;
        #pragma unroll
        for (int i = 0; i < 4; ++i) {
            int c = p * 4 + i;
            f32x4 a  = *(const f32x4*)(s0 + c * 8);
            f32x4 bb = *(const f32x4*)(s0 + c * 8 + 4);
            f32x4 pa = *(const f32x4*)(s1 + c * 8);
            f32x4 pb = *(const f32x4*)(s1 + c * 8 + 4);
            a += pa; bb += pb;
            s16x8 o;
            o[0]=f2bf(a[0]);  o[1]=f2bf(a[1]);  o[2]=f2bf(a[2]);  o[3]=f2bf(a[3]);
            o[4]=f2bf(bb[0]); o[5]=f2bf(bb[1]); o[6]=f2bf(bb[2]); o[7]=f2bf(bb[3]);
            int cs = c ^ (r & 7);
            *(s16x8*)(alds + r * 256 + cs * 8) = o;
        }
    }
    __syncthreads();

    const int w = t >> 6, lane = t & 63;
    const int lrow = lane & 15, lgrp = lane >> 4;
    const int wc = w * 64;                        // wave owns cols [wc, wc+64)

    float biasq[4];
    #pragma unroll
    for (int nf = 0; nf < 4; ++nf) biasq[nf] = bq[wc + nf * 16 + lrow];

    f32x4 acc[2][4];
    #pragma unroll
    for (int mf = 0; mf < 2; ++mf)
        #pragma unroll
        for (int nf = 0; nf < 4; ++nf) acc[mf][nf] = (f32x4){0.f, 0.f, 0.f, 0.f};

    #pragma unroll
    for (int ks = 0; ks < 8; ++ks) {
        s16x8 af[2];
        #pragma unroll
        for (int mf = 0; mf < 2; ++mf) {
            int rr = mf * 16 + lrow;
            int cs = (ks * 4 + lgrp) ^ (rr & 7);
            af[mf] = *(const s16x8*)(alds + rr * 256 + cs * 8);
        }
        #pragma unroll
        for (int nf = 0; nf < 4; ++nf) {
            s16x8 bfr = *(const s16x8*)(wq_bf + (size_t)(wc + nf * 16 + lrow) * 256
                                              + ks * 32 + lgrp * 8);
            acc[0][nf] = MFMA16(af[0], bfr, acc[0][nf]);
            acc[1][nf] = MFMA16(af[1], bfr, acc[1][nf]);
        }
    }

    // per-head softmax over 32 channels (no max-sub needed; |q| < ~4)
    short* ql = (short*)qlds[w];
    #pragma unroll
    for (int mf = 0; mf < 2; ++mf) {
        f32x4 e[4];
        #pragma unroll
        for (int nf = 0; nf < 4; ++nf)
            #pragma unroll
            for (int rr = 0; rr < 4; ++rr)
                e[nf][rr] = __expf(acc[mf][nf][rr] + biasq[nf]);
        #pragma unroll
        for (int hl = 0; hl < 2; ++hl) {
            #pragma unroll
            for (int rr = 0; rr < 4; ++rr) {
                float s = e[hl * 2][rr] + e[hl * 2 + 1][rr];
                s += __shfl_xor(s, 1);
                s += __shfl_xor(s, 2);
                s += __shfl_xor(s, 4);
                s += __shfl_xor(s, 8);
                float rinv = 1.0f / s;
                int row = mf * 16 + lgrp * 4 + rr;
                #pragma unroll
                for (int n2 = 0; n2 < 2; ++n2) {
                    int colc = hl * 32 + n2 * 16 + lrow;       // local col in 64
                    int cs = (colc >> 3) ^ (row & 7);
                    ql[row * 64 + cs * 8 + (colc & 7)] = f2bf(e[hl * 2 + n2][rr] * rinv);
                }
            }
        }
    }
    __syncthreads();   // drain LDS writes; also: all waves done reading alds

    // attend: att[32 x 64] = qsm @ ctx (per head)
    f32x4 att[2][2][2];
    #pragma unroll
    for (int hl = 0; hl < 2; ++hl)
        #pragma unroll
        for (int mf = 0; mf < 2; ++mf)
            #pragma unroll
            for (int n2 = 0; n2 < 2; ++n2) att[hl][mf][n2] = (f32x4){0.f,0.f,0.f,0.f};

    #pragma unroll
    for (int hl = 0; hl < 2; ++hl) {
        const short* cbase = ctxT + (size_t)(b * 8 + w * 2 + hl) * 1024;
        s16x8 bctx[2];
        #pragma unroll
        for (int n2 = 0; n2 < 2; ++n2)
            bctx[n2] = *(const s16x8*)(cbase + (n2 * 16 + lrow) * 32 + lgrp * 8);
        #pragma unroll
        for (int mf = 0; mf < 2; ++mf) {
            int row = mf * 16 + lrow;
            int cs = (hl * 4 + lgrp) ^ (row & 7);
            s16x8 aq = *(const s16x8*)(ql + row * 64 + cs * 8);
            #pragma unroll
            for (int n2 = 0; n2 < 2; ++n2)
                att[hl][mf][n2] = MFMA16(aq, bctx[n2], att[hl][mf][n2]);
        }
    }

    // attended -> alds (bf16, swizzled)
    #pragma unroll
    for (int hl = 0; hl < 2; ++hl)
      #pragma unroll
      for (int mf = 0; mf < 2; ++mf)
        #pragma unroll
        for (int n2 = 0; n2 < 2; ++n2)
          #pragma unroll
          for (int rr = 0; rr < 4; ++rr) {
              int row = mf * 16 + lgrp * 4 + rr;
              int col = wc + hl * 32 + n2 * 16 + lrow;
              int cs = (col >> 3) ^ (row & 7);
              alds[row * 256 + cs * 8 + (col & 7)] = f2bf(att[hl][mf][n2][rr]);
          }
    __syncthreads();

    // reprojection: out = attended @ Wr^T + br
    float biasr[4];
    #pragma unroll
    for (int nf = 0; nf < 4; ++nf) biasr[nf] = br[wc + nf * 16 + lrow];

    f32x4 acc2[2][4];
    #pragma unroll
    for (int mf = 0; mf < 2; ++mf)
        #pragma unroll
        for (int nf = 0; nf < 4; ++nf) acc2[mf][nf] = (f32x4){0.f, 0.f, 0.f, 0.f};

    #pragma unroll
    for (int ks = 0; ks < 8; ++ks) {
        s16x8 af[2];
        #pragma unroll
        for (int mf = 0; mf < 2; ++mf) {
            int rr = mf * 16 + lrow;
            int cs = (ks * 4 + lgrp) ^ (rr & 7);
            af[mf] = *(const s16x8*)(alds + rr * 256 + cs * 8);
        }
        #pragma unroll
        for (int nf = 0; nf < 4; ++nf) {
            s16x8 bfr = *(const s16x8*)(wr_bf + (size_t)(wc + nf * 16 + lrow) * 256
                                              + ks * 32 + lgrp * 8);
            acc2[0][nf] = MFMA16(af[0], bfr, acc2[0][nf]);
            acc2[1][nf] = MFMA16(af[1], bfr, acc2[1][nf]);
        }
    }

    #pragma unroll
    for (int mf = 0; mf < 2; ++mf)
      #pragma unroll
      for (int nf = 0; nf < 4; ++nf)
        #pragma unroll
        for (int rr = 0; rr < 4; ++rr) {
            int grow = row0 + mf * 16 + lgrp * 4 + rr;
            out[(size_t)grow * 256 + wc + nf * 16 + lrow] = acc2[mf][nf][rr] + biasr[nf];
        }
}

// ---------------------------------------------------------------------------
extern "C" void kernel_launch(void* const* d_in, const int* in_sizes, int n_in,
                              void* d_out, int out_size, void* d_ws, size_t ws_size,
                              hipStream_t stream)
{
    const float* x    = (const float*)d_in[0];
    const float* y    = (const float*)d_in[1];
    const float* xpos = (const float*)d_in[2];
    const float* ypos = (const float*)d_in[3];
    const float* Wq   = (const float*)d_in[4];
    const float* bq   = (const float*)d_in[5];
    const float* Wk   = (const float*)d_in[6];
    const float* bk   = (const float*)d_in[7];
    const float* Wv   = (const float*)d_in[8];
    const float* bv   = (const float*)d_in[9];
    const float* Wr   = (const float*)d_in[10];
    const float* br   = (const float*)d_in[11];

    char*  ws    = (char*)d_ws;
    short* wbf   = (short*)(ws);                    // 4 x 65536 bf16 (512 KB)
    short* ctxT  = (short*)(ws + 524288);           // 32*1024 bf16 (64 KB)
    float* parts = (float*)(ws + (1 << 20));        // 512*1056 f32 (~2.2 MB)
    short* e_buf = (short*)(ws + ((size_t)4 << 20)); // 65536*256 bf16 (33.5 MB)
    short* v_buf = e_buf + (size_t)65536 * 256;      // 33.5 MB
    float* outp  = (float*)d_out;

    hipLaunchKernelGGL(wcvt_kernel, dim3(256), dim3(256), 0, stream,
                       Wq, Wk, Wv, Wr, wbf);
    hipLaunchKernelGGL(kv_kernel, dim3(2048), dim3(256), 0, stream,
                       y, ypos, wbf + 65536, wbf + 131072, bk, bv, e_buf, v_buf);
    hipLaunchKernelGGL(ctx_kernel, dim3(16, 32), dim3(256), 0, stream,
                       e_buf, v_buf, parts);
    hipLaunchKernelGGL(ctx_reduce_kernel, dim3(32), dim3(256), 0, stream,
                       parts, ctxT);
    hipLaunchKernelGGL(qout_kernel, dim3(2048), dim3(256), 0, stream,
                       x, xpos, wbf, bq, ctxT, wbf + 196608, br, outp);
}

// Round 9
// 169.861 us; speedup vs baseline: 1.4934x; 1.4934x over previous
//
#include <hip/hip_runtime.h>

// Efficient (linear) attention, fused MFMA implementation for gfx950.  v5-r8
// B=4, NX=NY=16384, C=256, H=8, dk=dv=32.  M = B*N = 65536 rows.
// R3 change (resubmitted; r7 died on infra): kill scattered per-fragment VMEM.
// Weights pre-packed into MFMA fragment order (lane-consecutive 1KB per
// (tile,ks)); A staged via full-row coalesced loads into XOR-swizzled LDS.
// kv -> 64-row/512-thr blocks.

typedef float f32x4 __attribute__((ext_vector_type(4)));
typedef short s16x4 __attribute__((ext_vector_type(4)));
typedef short s16x8 __attribute__((ext_vector_type(8)));

#define MFMA16(A, B, C) __builtin_amdgcn_mfma_f32_16x16x32_bf16((A), (B), (C), 0, 0, 0)

__device__ __forceinline__ short f2bf(float f) {
    unsigned u = __builtin_bit_cast(unsigned, f);
    u = (u + 0x7FFFu + ((u >> 16) & 1u)) >> 16;   // RNE
    return (short)u;
}
__device__ __forceinline__ float bf2f(short b) {
    unsigned u = ((unsigned)(unsigned short)b) << 16;
    return __builtin_bit_cast(float, u);
}

// ---------------------------------------------------------------------------
// K0: convert 4 weight matrices to bf16 in MFMA-fragment-packed order.
// packed[m][tile][ks][lane][8] ; element = W[tile*16 + (lane&15)][ks*32 + (lane>>4)*8 + j]
// A B-frag load is then base + lane*16B : fully lane-consecutive (16 full lines).
// ---------------------------------------------------------------------------
__global__ __launch_bounds__(256) void wcvt_kernel(
    const float* __restrict__ wq, const float* __restrict__ wk,
    const float* __restrict__ wv, const float* __restrict__ wr,
    short* __restrict__ wbf)
{
    int id = blockIdx.x * 256 + threadIdx.x;     // grid 128 -> 32768 frag-slots
    int m = id >> 13;                            // matrix
    int slot = id & 8191;                        // tile(4b) ks(3b) lane(6b)
    int tile = slot >> 9;
    int ks   = (slot >> 6) & 7;
    int lane = slot & 63;
    int lrow = lane & 15, lgrp = lane >> 4;
    const float* src = (m == 0) ? wq : (m == 1) ? wk : (m == 2) ? wv : wr;
    const float* p = src + (size_t)(tile * 16 + lrow) * 256 + ks * 32 + lgrp * 8;
    f32x4 a = *(const f32x4*)p;
    f32x4 b = *(const f32x4*)(p + 4);
    s16x8 o;
    o[0]=f2bf(a[0]); o[1]=f2bf(a[1]); o[2]=f2bf(a[2]); o[3]=f2bf(a[3]);
    o[4]=f2bf(b[0]); o[5]=f2bf(b[1]); o[6]=f2bf(b[2]); o[7]=f2bf(b[3]);
    *(s16x8*)(wbf + (size_t)id * 8) = o;
}

// ---------------------------------------------------------------------------
// K1: e = exp((y+ypos) @ Wk^T + bk), v = y @ Wv^T + bv   -> bf16 buffers
// 512 thr (8 waves), 64-row tile, grid 1024. Stage: each wave loads FULL 1KB
// rows (lane l -> bytes l*16), converts, writes both ak (y+ypos) and av (y)
// into XOR-swizzled LDS. Wave w: is_k=(w<4), rowhalf=(w>>1)&1, colhalf=w&1.
// B-frags from packed weights: lane-consecutive 16B loads.
// ---------------------------------------------------------------------------
__global__ __launch_bounds__(512, 4) void kv_kernel(
    const float* __restrict__ y, const float* __restrict__ ypos,
    const short* __restrict__ wkp, const short* __restrict__ wvp,
    const float* __restrict__ bk, const float* __restrict__ bv,
    short* __restrict__ e_buf, short* __restrict__ v_buf)
{
    __shared__ short ak[64 * 256];               // bf16(y+ypos), chunk ^= (row&7)
    __shared__ short av[64 * 256];               // bf16(y)
    const int row0 = blockIdx.x * 64;
    const int t = threadIdx.x;
    const int w = t >> 6, lane = t & 63;

    { // stage 64 rows; one full row per wave-instruction
        #pragma unroll
        for (int it = 0; it < 8; ++it) {
            int r = it * 8 + w;
            const float* sy = y    + (size_t)(row0 + r) * 256 + lane * 4;
            const float* sp = ypos + (size_t)(row0 + r) * 256 + lane * 4;
            f32x4 a = *(const f32x4*)sy;
            f32x4 p = *(const f32x4*)sp;
            f32x4 k = a + p;
            s16x4 ov, ok;
            ov[0]=f2bf(a[0]); ov[1]=f2bf(a[1]); ov[2]=f2bf(a[2]); ov[3]=f2bf(a[3]);
            ok[0]=f2bf(k[0]); ok[1]=f2bf(k[1]); ok[2]=f2bf(k[2]); ok[3]=f2bf(k[3]);
            int swz = ((lane >> 1) ^ (r & 7)) * 8 + (lane & 1) * 4;
            *(s16x4*)(av + r * 256 + swz) = ov;
            *(s16x4*)(ak + r * 256 + swz) = ok;
        }
    }
    __syncthreads();

    const int lrow = lane & 15, lgrp = lane >> 4;
    const bool is_k = (w < 4);                   // wave-uniform
    const int wrow0 = ((w >> 1) & 1) * 32;
    const int colbase = (w & 1) * 128;
    const short* WP = is_k ? wkp : wvp;          // packed
    const float* bp = is_k ? bk : bv;
    short* obuf = is_k ? e_buf : v_buf;
    const short* A = is_k ? ak : av;

    float bias[8];
    #pragma unroll
    for (int nf = 0; nf < 8; ++nf) bias[nf] = bp[colbase + nf * 16 + lrow];

    // A-frags from LDS (resident): af[mf][ks]
    s16x8 af[2][8];
    #pragma unroll
    for (int mf = 0; mf < 2; ++mf) {
        int rr = wrow0 + mf * 16 + lrow;
        #pragma unroll
        for (int ks = 0; ks < 8; ++ks) {
            int cs = ((ks * 4 + lgrp) ^ (rr & 7));
            af[mf][ks] = *(const s16x8*)(A + rr * 256 + cs * 8);
        }
    }

    #pragma unroll
    for (int nf = 0; nf < 8; ++nf) {
        const int tile = (colbase >> 4) + nf;
        const short* wt = WP + ((size_t)tile * 8) * 512 + lane * 8;
        f32x4 a0 = (f32x4){0.f, 0.f, 0.f, 0.f};
        f32x4 a1 = (f32x4){0.f, 0.f, 0.f, 0.f};
        #pragma unroll
        for (int kg = 0; kg < 2; ++kg) {         // batch B by 4 (VGPR pressure)
            s16x8 bf[4];
            #pragma unroll
            for (int kk = 0; kk < 4; ++kk)
                bf[kk] = *(const s16x8*)(wt + (kg * 4 + kk) * 512);
            #pragma unroll
            for (int kk = 0; kk < 4; ++kk) {
                a0 = MFMA16(af[0][kg * 4 + kk], bf[kk], a0);
                a1 = MFMA16(af[1][kg * 4 + kk], bf[kk], a1);
            }
        }
        const int col = colbase + nf * 16 + lrow;
        #pragma unroll
        for (int rr = 0; rr < 4; ++rr) {
            int g0 = row0 + wrow0 + lgrp * 4 + rr;
            float v0 = a0[rr] + bias[nf];
            float v1 = a1[rr] + bias[nf];
            if (is_k) { v0 = __expf(v0); v1 = __expf(v1); }
            obuf[(size_t)g0 * 256 + col]        = f2bf(v0);
            obuf[(size_t)(g0 + 16) * 256 + col] = f2bf(v1);
        }
    }
}

// ---------------------------------------------------------------------------
// K2: ctx partials.  grid (16 chunks, 32 bh).  block 256 thr.  (unchanged)
// ---------------------------------------------------------------------------
__global__ __launch_bounds__(256) void ctx_kernel(
    const short* __restrict__ e_buf, const short* __restrict__ v_buf,
    float* __restrict__ partials)
{
    __shared__ float se[128 * 32];
    __shared__ float sv[128 * 32];
    __shared__ float red[4 * 1056];
    const int cb = blockIdx.x, bh = blockIdx.y;
    const int b = bh >> 3, h = bh & 7;
    const int tok0 = b * 16384 + cb * 1024;
    const int t = threadIdx.x, w = t >> 6, lane = t & 63;
    const int ckb = (lane >> 3) * 4, cvb = (lane & 7) * 4;

    f32x4 acc[4];
    #pragma unroll
    for (int i = 0; i < 4; ++i) acc[i] = (f32x4){0.f, 0.f, 0.f, 0.f};
    f32x4 dn = (f32x4){0.f, 0.f, 0.f, 0.f};

    for (int it = 0; it < 8; ++it) {
        __syncthreads();
        #pragma unroll
        for (int s = 0; s < 2; ++s) {
            int id = t + s * 256;
            int rr = id >> 2, pp = id & 3;
            size_t g = (size_t)(tok0 + it * 128 + rr) * 256 + h * 32 + pp * 8;
            s16x8 ee = *(const s16x8*)(e_buf + g);
            s16x8 vv = *(const s16x8*)(v_buf + g);
            f32x4 e0 = {bf2f(ee[0]), bf2f(ee[1]), bf2f(ee[2]), bf2f(ee[3])};
            f32x4 e1 = {bf2f(ee[4]), bf2f(ee[5]), bf2f(ee[6]), bf2f(ee[7])};
            f32x4 v0 = {bf2f(vv[0]), bf2f(vv[1]), bf2f(vv[2]), bf2f(vv[3])};
            f32x4 v1 = {bf2f(vv[4]), bf2f(vv[5]), bf2f(vv[6]), bf2f(vv[7])};
            *(f32x4*)(se + rr * 32 + pp * 8)     = e0;
            *(f32x4*)(se + rr * 32 + pp * 8 + 4) = e1;
            *(f32x4*)(sv + rr * 32 + pp * 8)     = v0;
            *(f32x4*)(sv + rr * 32 + pp * 8 + 4) = v1;
        }
        __syncthreads();
        const int r0 = w * 32;
        #pragma unroll 8
        for (int rr = 0; rr < 32; ++rr) {
            f32x4 e4 = *(const f32x4*)(se + (r0 + rr) * 32 + ckb);
            f32x4 v4 = *(const f32x4*)(sv + (r0 + rr) * 32 + cvb);
            acc[0] += e4[0] * v4;
            acc[1] += e4[1] * v4;
            acc[2] += e4[2] * v4;
            acc[3] += e4[3] * v4;
            dn += e4;
        }
    }
    __syncthreads();
    #pragma unroll
    for (int i = 0; i < 4; ++i)
        *(f32x4*)(red + w * 1056 + (ckb + i) * 32 + cvb) = acc[i];
    if ((lane & 7) == 0)
        *(f32x4*)(red + w * 1056 + 1024 + ckb) = dn;
    __syncthreads();
    float* outp = partials + (size_t)(bh * 16 + cb) * 1056;
    for (int e = t; e < 1056; e += 256)
        outp[e] = red[e] + red[1056 + e] + red[2112 + e] + red[3168 + e];
}

// K2b: reduce 16 chunks, normalize, write ctx^T bf16 [bh][cv][ck]  (unchanged)
__global__ __launch_bounds__(256) void ctx_reduce_kernel(
    const float* __restrict__ partials, short* __restrict__ ctxT)
{
    __shared__ float s[1056];
    const int bh = blockIdx.x, t = threadIdx.x;
    for (int e = t; e < 1056; e += 256) {
        float a = 0.f;
        for (int c = 0; c < 16; ++c) a += partials[(size_t)(bh * 16 + c) * 1056 + e];
        s[e] = a;
    }
    __syncthreads();
    for (int e = t; e < 1024; e += 256) {
        int ck = e >> 5, cv = e & 31;
        float val = s[e] / s[1024 + ck];
        ctxT[(size_t)bh * 1024 + cv * 32 + ck] = f2bf(val);
    }
}

// ---------------------------------------------------------------------------
// K3: fused q pass.  256 thr, 32 rows, grid 2048.  Coalesced row staging +
// packed Wq/Wr fragment loads; softmax/attend/reproject logic unchanged.
// ---------------------------------------------------------------------------
__global__ __launch_bounds__(256, 4) void qout_kernel(
    const float* __restrict__ x, const float* __restrict__ xpos,
    const short* __restrict__ wqp, const float* __restrict__ bq,
    const short* __restrict__ ctxT,
    const short* __restrict__ wrp, const float* __restrict__ br,
    float* __restrict__ out)
{
    __shared__ short alds[32 * 256];             // x-tile, then attended (swizzled)
    __shared__ short qlds[4][32 * 64];           // per-wave softmaxed q (swizzled)
    const int row0 = blockIdx.x * 32;
    const int b = row0 >> 14;
    const int t = threadIdx.x;
    const int w = t >> 6, lane = t & 63;

    { // stage bf16(x+xpos): one full row per wave-instruction
        #pragma unroll
        for (int it = 0; it < 8; ++it) {
            int r = it * 4 + w;
            const float* sx = x    + (size_t)(row0 + r) * 256 + lane * 4;
            const float* sp = xpos + (size_t)(row0 + r) * 256 + lane * 4;
            f32x4 a = *(const f32x4*)sx;
            f32x4 p = *(const f32x4*)sp;
            a += p;
            s16x4 o;
            o[0]=f2bf(a[0]); o[1]=f2bf(a[1]); o[2]=f2bf(a[2]); o[3]=f2bf(a[3]);
            int swz = ((lane >> 1) ^ (r & 7)) * 8 + (lane & 1) * 4;
            *(s16x4*)(alds + r * 256 + swz) = o;
        }
    }
    __syncthreads();

    const int lrow = lane & 15, lgrp = lane >> 4;
    const int wc = w * 64;                        // wave owns cols [wc, wc+64)

    float biasq[4];
    #pragma unroll
    for (int nf = 0; nf < 4; ++nf) biasq[nf] = bq[wc + nf * 16 + lrow];

    f32x4 acc[2][4];
    #pragma unroll
    for (int mf = 0; mf < 2; ++mf)
        #pragma unroll
        for (int nf = 0; nf < 4; ++nf) acc[mf][nf] = (f32x4){0.f, 0.f, 0.f, 0.f};

    #pragma unroll
    for (int ks = 0; ks < 8; ++ks) {
        s16x8 af[2];
        #pragma unroll
        for (int mf = 0; mf < 2; ++mf) {
            int rr = mf * 16 + lrow;
            int cs = (ks * 4 + lgrp) ^ (rr & 7);
            af[mf] = *(const s16x8*)(alds + rr * 256 + cs * 8);
        }
        #pragma unroll
        for (int nf = 0; nf < 4; ++nf) {
            int tile = (wc >> 4) + nf;
            s16x8 bfr = *(const s16x8*)(wqp + ((size_t)tile * 8 + ks) * 512 + lane * 8);
            acc[0][nf] = MFMA16(af[0], bfr, acc[0][nf]);
            acc[1][nf] = MFMA16(af[1], bfr, acc[1][nf]);
        }
    }

    // per-head softmax over 32 channels (no max-sub needed; |q| < ~4)
    short* ql = (short*)qlds[w];
    #pragma unroll
    for (int mf = 0; mf < 2; ++mf) {
        f32x4 e[4];
        #pragma unroll
        for (int nf = 0; nf < 4; ++nf)
            #pragma unroll
            for (int rr = 0; rr < 4; ++rr)
                e[nf][rr] = __expf(acc[mf][nf][rr] + biasq[nf]);
        #pragma unroll
        for (int hl = 0; hl < 2; ++hl) {
            #pragma unroll
            for (int rr = 0; rr < 4; ++rr) {
                float s = e[hl * 2][rr] + e[hl * 2 + 1][rr];
                s += __shfl_xor(s, 1);
                s += __shfl_xor(s, 2);
                s += __shfl_xor(s, 4);
                s += __shfl_xor(s, 8);
                float rinv = 1.0f / s;
                int row = mf * 16 + lgrp * 4 + rr;
                #pragma unroll
                for (int n2 = 0; n2 < 2; ++n2) {
                    int colc = hl * 32 + n2 * 16 + lrow;
                    int cs = (colc >> 3) ^ (row & 7);
                    ql[row * 64 + cs * 8 + (colc & 7)] = f2bf(e[hl * 2 + n2][rr] * rinv);
                }
            }
        }
    }
    __syncthreads();

    // attend: att[32 x 64] = qsm @ ctx (per head)
    f32x4 att[2][2][2];
    #pragma unroll
    for (int hl = 0; hl < 2; ++hl)
        #pragma unroll
        for (int mf = 0; mf < 2; ++mf)
            #pragma unroll
            for (int n2 = 0; n2 < 2; ++n2) att[hl][mf][n2] = (f32x4){0.f,0.f,0.f,0.f};

    #pragma unroll
    for (int hl = 0; hl < 2; ++hl) {
        const short* cbase = ctxT + (size_t)(b * 8 + w * 2 + hl) * 1024;
        s16x8 bctx[2];
        #pragma unroll
        for (int n2 = 0; n2 < 2; ++n2)
            bctx[n2] = *(const s16x8*)(cbase + (n2 * 16 + lrow) * 32 + lgrp * 8);
        #pragma unroll
        for (int mf = 0; mf < 2; ++mf) {
            int row = mf * 16 + lrow;
            int cs = (hl * 4 + lgrp) ^ (row & 7);
            s16x8 aq = *(const s16x8*)(ql + row * 64 + cs * 8);
            #pragma unroll
            for (int n2 = 0; n2 < 2; ++n2)
                att[hl][mf][n2] = MFMA16(aq, bctx[n2], att[hl][mf][n2]);
        }
    }

    // attended -> alds (bf16, swizzled)
    #pragma unroll
    for (int hl = 0; hl < 2; ++hl)
      #pragma unroll
      for (int mf = 0; mf < 2; ++mf)
        #pragma unroll
        for (int n2 = 0; n2 < 2; ++n2)
          #pragma unroll
          for (int rr = 0; rr < 4; ++rr) {
              int row = mf * 16 + lgrp * 4 + rr;
              int col = wc + hl * 32 + n2 * 16 + lrow;
              int cs = (col >> 3) ^ (row & 7);
              alds[row * 256 + cs * 8 + (col & 7)] = f2bf(att[hl][mf][n2][rr]);
          }
    __syncthreads();

    // reprojection: out = attended @ Wr^T + br
    float biasr[4];
    #pragma unroll
    for (int nf = 0; nf < 4; ++nf) biasr[nf] = br[wc + nf * 16 + lrow];

    f32x4 acc2[2][4];
    #pragma unroll
    for (int mf = 0; mf < 2; ++mf)
        #pragma unroll
        for (int nf = 0; nf < 4; ++nf) acc2[mf][nf] = (f32x4){0.f, 0.f, 0.f, 0.f};

    #pragma unroll
    for (int ks = 0; ks < 8; ++ks) {
        s16x8 af[2];
        #pragma unroll
        for (int mf = 0; mf < 2; ++mf) {
            int rr = mf * 16 + lrow;
            int cs = (ks * 4 + lgrp) ^ (rr & 7);
            af[mf] = *(const s16x8*)(alds + rr * 256 + cs * 8);
        }
        #pragma unroll
        for (int nf = 0; nf < 4; ++nf) {
            int tile = (wc >> 4) + nf;
            s16x8 bfr = *(const s16x8*)(wrp + ((size_t)tile * 8 + ks) * 512 + lane * 8);
            acc2[0][nf] = MFMA16(af[0], bfr, acc2[0][nf]);
            acc2[1][nf] = MFMA16(af[1], bfr, acc2[1][nf]);
        }
    }

    #pragma unroll
    for (int mf = 0; mf < 2; ++mf)
      #pragma unroll
      for (int nf = 0; nf < 4; ++nf)
        #pragma unroll
        for (int rr = 0; rr < 4; ++rr) {
            int grow = row0 + mf * 16 + lgrp * 4 + rr;
            out[(size_t)grow * 256 + wc + nf * 16 + lrow] = acc2[mf][nf][rr] + biasr[nf];
        }
}

// ---------------------------------------------------------------------------
extern "C" void kernel_launch(void* const* d_in, const int* in_sizes, int n_in,
                              void* d_out, int out_size, void* d_ws, size_t ws_size,
                              hipStream_t stream)
{
    const float* x    = (const float*)d_in[0];
    const float* y    = (const float*)d_in[1];
    const float* xpos = (const float*)d_in[2];
    const float* ypos = (const float*)d_in[3];
    const float* Wq   = (const float*)d_in[4];
    const float* bq   = (const float*)d_in[5];
    const float* Wk   = (const float*)d_in[6];
    const float* bk   = (const float*)d_in[7];
    const float* Wv   = (const float*)d_in[8];
    const float* bv   = (const float*)d_in[9];
    const float* Wr   = (const float*)d_in[10];
    const float* br   = (const float*)d_in[11];

    char*  ws    = (char*)d_ws;
    short* wbf   = (short*)(ws);                    // 4 x 65536 bf16 packed (512 KB)
    short* ctxT  = (short*)(ws + 524288);           // 32*1024 bf16 (64 KB)
    float* parts = (float*)(ws + (1 << 20));        // 512*1056 f32 (~2.2 MB)
    short* e_buf = (short*)(ws + ((size_t)4 << 20)); // 65536*256 bf16 (33.5 MB)
    short* v_buf = e_buf + (size_t)65536 * 256;      // 33.5 MB
    float* outp  = (float*)d_out;

    hipLaunchKernelGGL(wcvt_kernel, dim3(128), dim3(256), 0, stream,
                       Wq, Wk, Wv, Wr, wbf);
    hipLaunchKernelGGL(kv_kernel, dim3(1024), dim3(512), 0, stream,
                       y, ypos, wbf + 65536, wbf + 131072, bk, bv, e_buf, v_buf);
    hipLaunchKernelGGL(ctx_kernel, dim3(16, 32), dim3(256), 0, stream,
                       e_buf, v_buf, parts);
    hipLaunchKernelGGL(ctx_reduce_kernel, dim3(32), dim3(256), 0, stream,
                       parts, ctxT);
    hipLaunchKernelGGL(qout_kernel, dim3(2048), dim3(256), 0, stream,
                       x, xpos, wbf, bq, ctxT, wbf + 196608, br, outp);
}

// Round 10
// 169.092 us; speedup vs baseline: 1.5002x; 1.0045x over previous
//
#include <hip/hip_runtime.h>

// Efficient (linear) attention, fused MFMA implementation for gfx950.  v6-r9
// B=4, NX=NY=16384, C=256, H=8, dk=dv=32.  M = B*N = 65536 rows.
// R4 change (kv only): 32-row/256-thr/32KB blocks (5 blocks/CU occupancy) +
// LDS-bounced coalesced C stores (full 1KB-row vector stores, no 2B scatter).

typedef float f32x4 __attribute__((ext_vector_type(4)));
typedef short s16x4 __attribute__((ext_vector_type(4)));
typedef short s16x8 __attribute__((ext_vector_type(8)));

#define MFMA16(A, B, C) __builtin_amdgcn_mfma_f32_16x16x32_bf16((A), (B), (C), 0, 0, 0)

__device__ __forceinline__ short f2bf(float f) {
    unsigned u = __builtin_bit_cast(unsigned, f);
    u = (u + 0x7FFFu + ((u >> 16) & 1u)) >> 16;   // RNE
    return (short)u;
}
__device__ __forceinline__ float bf2f(short b) {
    unsigned u = ((unsigned)(unsigned short)b) << 16;
    return __builtin_bit_cast(float, u);
}

// ---------------------------------------------------------------------------
// K0: convert 4 weight matrices to bf16 in MFMA-fragment-packed order.
// packed[m][tile][ks][lane][8] ; element = W[tile*16 + (lane&15)][ks*32 + (lane>>4)*8 + j]
// ---------------------------------------------------------------------------
__global__ __launch_bounds__(256) void wcvt_kernel(
    const float* __restrict__ wq, const float* __restrict__ wk,
    const float* __restrict__ wv, const float* __restrict__ wr,
    short* __restrict__ wbf)
{
    int id = blockIdx.x * 256 + threadIdx.x;     // grid 128 -> 32768 frag-slots
    int m = id >> 13;                            // matrix
    int slot = id & 8191;                        // tile(4b) ks(3b) lane(6b)
    int tile = slot >> 9;
    int ks   = (slot >> 6) & 7;
    int lane = slot & 63;
    int lrow = lane & 15, lgrp = lane >> 4;
    const float* src = (m == 0) ? wq : (m == 1) ? wk : (m == 2) ? wv : wr;
    const float* p = src + (size_t)(tile * 16 + lrow) * 256 + ks * 32 + lgrp * 8;
    f32x4 a = *(const f32x4*)p;
    f32x4 b = *(const f32x4*)(p + 4);
    s16x8 o;
    o[0]=f2bf(a[0]); o[1]=f2bf(a[1]); o[2]=f2bf(a[2]); o[3]=f2bf(a[3]);
    o[4]=f2bf(b[0]); o[5]=f2bf(b[1]); o[6]=f2bf(b[2]); o[7]=f2bf(b[3]);
    *(s16x8*)(wbf + (size_t)id * 8) = o;
}

// ---------------------------------------------------------------------------
// K1: e = exp((y+ypos) @ Wk^T + bk), v = y @ Wv^T + bv   -> bf16 buffers
// 256 thr (4 waves), 32-row tile, grid 2048, 32KB LDS (5 blocks/CU).
// Phase 1: stage bf16(y+ypos) [ak] and bf16(y) [av], XOR-swizzled.
// Phase 2: A-frags -> regs; barrier.
// Phase 3: per nf: packed-B loads + 16 MFMA -> bias/exp -> C to LDS
//          (chunk-swizzled [32][512] reusing the staging buffer).
// Phase 4: barrier; coalesced stores: wave w, iter i -> full row i*4+w,
//          lanes 0..31 -> e_buf 16B each, lanes 32..63 -> v_buf.
// ---------------------------------------------------------------------------
__global__ __launch_bounds__(256, 4) void kv_kernel(
    const float* __restrict__ y, const float* __restrict__ ypos,
    const short* __restrict__ wkp, const short* __restrict__ wvp,
    const float* __restrict__ bk, const float* __restrict__ bv,
    short* __restrict__ e_buf, short* __restrict__ v_buf)
{
    __shared__ short smem[32 * 512];             // 32KB, dual-purpose
    short* ak = smem;                            // [32][256] swizzled bf16(y+ypos)
    short* av = smem + 32 * 256;                 // [32][256] swizzled bf16(y)
    const int row0 = blockIdx.x * 32;
    const int t = threadIdx.x;
    const int w = t >> 6, lane = t & 63;

    { // stage 32 rows; one full 1KB row per wave-instruction
        #pragma unroll
        for (int it = 0; it < 8; ++it) {
            int r = it * 4 + w;
            const float* sy = y    + (size_t)(row0 + r) * 256 + lane * 4;
            const float* sp = ypos + (size_t)(row0 + r) * 256 + lane * 4;
            f32x4 a = *(const f32x4*)sy;
            f32x4 p = *(const f32x4*)sp;
            f32x4 k = a + p;
            s16x4 ov, ok;
            ov[0]=f2bf(a[0]); ov[1]=f2bf(a[1]); ov[2]=f2bf(a[2]); ov[3]=f2bf(a[3]);
            ok[0]=f2bf(k[0]); ok[1]=f2bf(k[1]); ok[2]=f2bf(k[2]); ok[3]=f2bf(k[3]);
            int swz = ((lane >> 1) ^ (r & 7)) * 8 + (lane & 1) * 4;
            *(s16x4*)(av + r * 256 + swz) = ov;
            *(s16x4*)(ak + r * 256 + swz) = ok;
        }
    }
    __syncthreads();

    const int lrow = lane & 15, lgrp = lane >> 4;
    const bool is_k = (w < 2);                   // wave-uniform
    const int colbase = (w & 1) * 128;
    const short* WP = is_k ? wkp : wvp;          // packed
    const float* bp = is_k ? bk : bv;
    const short* A = is_k ? ak : av;

    float bias[8];
    #pragma unroll
    for (int nf = 0; nf < 8; ++nf) bias[nf] = bp[colbase + nf * 16 + lrow];

    // A-frags from LDS into registers: af[mf][ks]
    s16x8 af[2][8];
    #pragma unroll
    for (int mf = 0; mf < 2; ++mf) {
        int rr = mf * 16 + lrow;
        #pragma unroll
        for (int ks = 0; ks < 8; ++ks) {
            int cs = ((ks * 4 + lgrp) ^ (rr & 7));
            af[mf][ks] = *(const s16x8*)(A + rr * 256 + cs * 8);
        }
    }
    __syncthreads();   // all waves have A in regs; smem is now reusable for C

    #pragma unroll
    for (int nf = 0; nf < 8; ++nf) {
        const int tile = (colbase >> 4) + nf;
        const short* wt = WP + ((size_t)tile * 8) * 512 + lane * 8;
        f32x4 a0 = (f32x4){0.f, 0.f, 0.f, 0.f};
        f32x4 a1 = (f32x4){0.f, 0.f, 0.f, 0.f};
        #pragma unroll
        for (int kg = 0; kg < 2; ++kg) {         // batch B by 4 (VGPR pressure)
            s16x8 bf[4];
            #pragma unroll
            for (int kk = 0; kk < 4; ++kk)
                bf[kk] = *(const s16x8*)(wt + (kg * 4 + kk) * 512);
            #pragma unroll
            for (int kk = 0; kk < 4; ++kk) {
                a0 = MFMA16(af[0][kg * 4 + kk], bf[kk], a0);
                a1 = MFMA16(af[1][kg * 4 + kk], bf[kk], a1);
            }
        }
        // C -> LDS [32][512] bf16, 16B-chunk XOR swizzle: phys = (col'>>3)^(lr&7)
        const int colp = (is_k ? 0 : 256) + colbase + nf * 16 + lrow;  // 0..511
        #pragma unroll
        for (int rr = 0; rr < 4; ++rr) {
            float v0 = a0[rr] + bias[nf];
            float v1 = a1[rr] + bias[nf];
            if (is_k) { v0 = __expf(v0); v1 = __expf(v1); }
            int lr0 = lgrp * 4 + rr;             // mf=0 row
            int lr1 = lr0 + 16;                  // mf=1 row
            smem[lr0 * 512 + (((colp >> 3) ^ (lr0 & 7)) * 8) + (colp & 7)] = f2bf(v0);
            smem[lr1 * 512 + (((colp >> 3) ^ (lr1 & 7)) * 8) + (colp & 7)] = f2bf(v1);
        }
    }
    __syncthreads();

    { // coalesced store-out: iter i -> row i*4+w; lane chunk = lane^(r&7)
        #pragma unroll
        for (int i = 0; i < 8; ++i) {
            int r = i * 4 + w;
            int grow = row0 + r;
            s16x8 val = *(const s16x8*)(smem + r * 512 + (lane ^ (r & 7)) * 8);
            if (lane < 32)
                *(s16x8*)(e_buf + (size_t)grow * 256 + lane * 8) = val;
            else
                *(s16x8*)(v_buf + (size_t)grow * 256 + (lane - 32) * 8) = val;
        }
    }
}

// ---------------------------------------------------------------------------
// K2: ctx partials.  grid (16 chunks, 32 bh).  block 256 thr.  (unchanged)
// ---------------------------------------------------------------------------
__global__ __launch_bounds__(256) void ctx_kernel(
    const short* __restrict__ e_buf, const short* __restrict__ v_buf,
    float* __restrict__ partials)
{
    __shared__ float se[128 * 32];
    __shared__ float sv[128 * 32];
    __shared__ float red[4 * 1056];
    const int cb = blockIdx.x, bh = blockIdx.y;
    const int b = bh >> 3, h = bh & 7;
    const int tok0 = b * 16384 + cb * 1024;
    const int t = threadIdx.x, w = t >> 6, lane = t & 63;
    const int ckb = (lane >> 3) * 4, cvb = (lane & 7) * 4;

    f32x4 acc[4];
    #pragma unroll
    for (int i = 0; i < 4; ++i) acc[i] = (f32x4){0.f, 0.f, 0.f, 0.f};
    f32x4 dn = (f32x4){0.f, 0.f, 0.f, 0.f};

    for (int it = 0; it < 8; ++it) {
        __syncthreads();
        #pragma unroll
        for (int s = 0; s < 2; ++s) {
            int id = t + s * 256;
            int rr = id >> 2, pp = id & 3;
            size_t g = (size_t)(tok0 + it * 128 + rr) * 256 + h * 32 + pp * 8;
            s16x8 ee = *(const s16x8*)(e_buf + g);
            s16x8 vv = *(const s16x8*)(v_buf + g);
            f32x4 e0 = {bf2f(ee[0]), bf2f(ee[1]), bf2f(ee[2]), bf2f(ee[3])};
            f32x4 e1 = {bf2f(ee[4]), bf2f(ee[5]), bf2f(ee[6]), bf2f(ee[7])};
            f32x4 v0 = {bf2f(vv[0]), bf2f(vv[1]), bf2f(vv[2]), bf2f(vv[3])};
            f32x4 v1 = {bf2f(vv[4]), bf2f(vv[5]), bf2f(vv[6]), bf2f(vv[7])};
            *(f32x4*)(se + rr * 32 + pp * 8)     = e0;
            *(f32x4*)(se + rr * 32 + pp * 8 + 4) = e1;
            *(f32x4*)(sv + rr * 32 + pp * 8)     = v0;
            *(f32x4*)(sv + rr * 32 + pp * 8 + 4) = v1;
        }
        __syncthreads();
        const int r0 = w * 32;
        #pragma unroll 8
        for (int rr = 0; rr < 32; ++rr) {
            f32x4 e4 = *(const f32x4*)(se + (r0 + rr) * 32 + ckb);
            f32x4 v4 = *(const f32x4*)(sv + (r0 + rr) * 32 + cvb);
            acc[0] += e4[0] * v4;
            acc[1] += e4[1] * v4;
            acc[2] += e4[2] * v4;
            acc[3] += e4[3] * v4;
            dn += e4;
        }
    }
    __syncthreads();
    #pragma unroll
    for (int i = 0; i < 4; ++i)
        *(f32x4*)(red + w * 1056 + (ckb + i) * 32 + cvb) = acc[i];
    if ((lane & 7) == 0)
        *(f32x4*)(red + w * 1056 + 1024 + ckb) = dn;
    __syncthreads();
    float* outp = partials + (size_t)(bh * 16 + cb) * 1056;
    for (int e = t; e < 1056; e += 256)
        outp[e] = red[e] + red[1056 + e] + red[2112 + e] + red[3168 + e];
}

// K2b: reduce 16 chunks, normalize, write ctx^T bf16 [bh][cv][ck]  (unchanged)
__global__ __launch_bounds__(256) void ctx_reduce_kernel(
    const float* __restrict__ partials, short* __restrict__ ctxT)
{
    __shared__ float s[1056];
    const int bh = blockIdx.x, t = threadIdx.x;
    for (int e = t; e < 1056; e += 256) {
        float a = 0.f;
        for (int c = 0; c < 16; ++c) a += partials[(size_t)(bh * 16 + c) * 1056 + e];
        s[e] = a;
    }
    __syncthreads();
    for (int e = t; e < 1024; e += 256) {
        int ck = e >> 5, cv = e & 31;
        float val = s[e] / s[1024 + ck];
        ctxT[(size_t)bh * 1024 + cv * 32 + ck] = f2bf(val);
    }
}

// ---------------------------------------------------------------------------
// K3: fused q pass.  256 thr, 32 rows, grid 2048.  (unchanged from v5-r8)
// ---------------------------------------------------------------------------
__global__ __launch_bounds__(256, 4) void qout_kernel(
    const float* __restrict__ x, const float* __restrict__ xpos,
    const short* __restrict__ wqp, const float* __restrict__ bq,
    const short* __restrict__ ctxT,
    const short* __restrict__ wrp, const float* __restrict__ br,
    float* __restrict__ out)
{
    __shared__ short alds[32 * 256];             // x-tile, then attended (swizzled)
    __shared__ short qlds[4][32 * 64];           // per-wave softmaxed q (swizzled)
    const int row0 = blockIdx.x * 32;
    const int b = row0 >> 14;
    const int t = threadIdx.x;
    const int w = t >> 6, lane = t & 63;

    { // stage bf16(x+xpos): one full row per wave-instruction
        #pragma unroll
        for (int it = 0; it < 8; ++it) {
            int r = it * 4 + w;
            const float* sx = x    + (size_t)(row0 + r) * 256 + lane * 4;
            const float* sp = xpos + (size_t)(row0 + r) * 256 + lane * 4;
            f32x4 a = *(const f32x4*)sx;
            f32x4 p = *(const f32x4*)sp;
            a += p;
            s16x4 o;
            o[0]=f2bf(a[0]); o[1]=f2bf(a[1]); o[2]=f2bf(a[2]); o[3]=f2bf(a[3]);
            int swz = ((lane >> 1) ^ (r & 7)) * 8 + (lane & 1) * 4;
            *(s16x4*)(alds + r * 256 + swz) = o;
        }
    }
    __syncthreads();

    const int lrow = lane & 15, lgrp = lane >> 4;
    const int wc = w * 64;                        // wave owns cols [wc, wc+64)

    float biasq[4];
    #pragma unroll
    for (int nf = 0; nf < 4; ++nf) biasq[nf] = bq[wc + nf * 16 + lrow];

    f32x4 acc[2][4];
    #pragma unroll
    for (int mf = 0; mf < 2; ++mf)
        #pragma unroll
        for (int nf = 0; nf < 4; ++nf) acc[mf][nf] = (f32x4){0.f, 0.f, 0.f, 0.f};

    #pragma unroll
    for (int ks = 0; ks < 8; ++ks) {
        s16x8 af[2];
        #pragma unroll
        for (int mf = 0; mf < 2; ++mf) {
            int rr = mf * 16 + lrow;
            int cs = (ks * 4 + lgrp) ^ (rr & 7);
            af[mf] = *(const s16x8*)(alds + rr * 256 + cs * 8);
        }
        #pragma unroll
        for (int nf = 0; nf < 4; ++nf) {
            int tile = (wc >> 4) + nf;
            s16x8 bfr = *(const s16x8*)(wqp + ((size_t)tile * 8 + ks) * 512 + lane * 8);
            acc[0][nf] = MFMA16(af[0], bfr, acc[0][nf]);
            acc[1][nf] = MFMA16(af[1], bfr, acc[1][nf]);
        }
    }

    // per-head softmax over 32 channels (no max-sub needed; |q| < ~4)
    short* ql = (short*)qlds[w];
    #pragma unroll
    for (int mf = 0; mf < 2; ++mf) {
        f32x4 e[4];
        #pragma unroll
        for (int nf = 0; nf < 4; ++nf)
            #pragma unroll
            for (int rr = 0; rr < 4; ++rr)
                e[nf][rr] = __expf(acc[mf][nf][rr] + biasq[nf]);
        #pragma unroll
        for (int hl = 0; hl < 2; ++hl) {
            #pragma unroll
            for (int rr = 0; rr < 4; ++rr) {
                float s = e[hl * 2][rr] + e[hl * 2 + 1][rr];
                s += __shfl_xor(s, 1);
                s += __shfl_xor(s, 2);
                s += __shfl_xor(s, 4);
                s += __shfl_xor(s, 8);
                float rinv = 1.0f / s;
                int row = mf * 16 + lgrp * 4 + rr;
                #pragma unroll
                for (int n2 = 0; n2 < 2; ++n2) {
                    int colc = hl * 32 + n2 * 16 + lrow;
                    int cs = (colc >> 3) ^ (row & 7);
                    ql[row * 64 + cs * 8 + (colc & 7)] = f2bf(e[hl * 2 + n2][rr] * rinv);
                }
            }
        }
    }
    __syncthreads();

    // attend: att[32 x 64] = qsm @ ctx (per head)
    f32x4 att[2][2][2];
    #pragma unroll
    for (int hl = 0; hl < 2; ++hl)
        #pragma unroll
        for (int mf = 0; mf < 2; ++mf)
            #pragma unroll
            for (int n2 = 0; n2 < 2; ++n2) att[hl][mf][n2] = (f32x4){0.f,0.f,0.f,0.f};

    #pragma unroll
    for (int hl = 0; hl < 2; ++hl) {
        const short* cbase = ctxT + (size_t)(b * 8 + w * 2 + hl) * 1024;
        s16x8 bctx[2];
        #pragma unroll
        for (int n2 = 0; n2 < 2; ++n2)
            bctx[n2] = *(const s16x8*)(cbase + (n2 * 16 + lrow) * 32 + lgrp * 8);
        #pragma unroll
        for (int mf = 0; mf < 2; ++mf) {
            int row = mf * 16 + lrow;
            int cs = (hl * 4 + lgrp) ^ (row & 7);
            s16x8 aq = *(const s16x8*)(ql + row * 64 + cs * 8);
            #pragma unroll
            for (int n2 = 0; n2 < 2; ++n2)
                att[hl][mf][n2] = MFMA16(aq, bctx[n2], att[hl][mf][n2]);
        }
    }

    // attended -> alds (bf16, swizzled)
    #pragma unroll
    for (int hl = 0; hl < 2; ++hl)
      #pragma unroll
      for (int mf = 0; mf < 2; ++mf)
        #pragma unroll
        for (int n2 = 0; n2 < 2; ++n2)
          #pragma unroll
          for (int rr = 0; rr < 4; ++rr) {
              int row = mf * 16 + lgrp * 4 + rr;
              int col = wc + hl * 32 + n2 * 16 + lrow;
              int cs = (col >> 3) ^ (row & 7);
              alds[row * 256 + cs * 8 + (col & 7)] = f2bf(att[hl][mf][n2][rr]);
          }
    __syncthreads();

    // reprojection: out = attended @ Wr^T + br
    float biasr[4];
    #pragma unroll
    for (int nf = 0; nf < 4; ++nf) biasr[nf] = br[wc + nf * 16 + lrow];

    f32x4 acc2[2][4];
    #pragma unroll
    for (int mf = 0; mf < 2; ++mf)
        #pragma unroll
        for (int nf = 0; nf < 4; ++nf) acc2[mf][nf] = (f32x4){0.f, 0.f, 0.f, 0.f};

    #pragma unroll
    for (int ks = 0; ks < 8; ++ks) {
        s16x8 af[2];
        #pragma unroll
        for (int mf = 0; mf < 2; ++mf) {
            int rr = mf * 16 + lrow;
            int cs = (ks * 4 + lgrp) ^ (rr & 7);
            af[mf] = *(const s16x8*)(alds + rr * 256 + cs * 8);
        }
        #pragma unroll
        for (int nf = 0; nf < 4; ++nf) {
            int tile = (wc >> 4) + nf;
            s16x8 bfr = *(const s16x8*)(wrp + ((size_t)tile * 8 + ks) * 512 + lane * 8);
            acc2[0][nf] = MFMA16(af[0], bfr, acc2[0][nf]);
            acc2[1][nf] = MFMA16(af[1], bfr, acc2[1][nf]);
        }
    }

    #pragma unroll
    for (int mf = 0; mf < 2; ++mf)
      #pragma unroll
      for (int nf = 0; nf < 4; ++nf)
        #pragma unroll
        for (int rr = 0; rr < 4; ++rr) {
            int grow = row0 + mf * 16 + lgrp * 4 + rr;
            out[(size_t)grow * 256 + wc + nf * 16 + lrow] = acc2[mf][nf][rr] + biasr[nf];
        }
}

// ---------------------------------------------------------------------------
extern "C" void kernel_launch(void* const* d_in, const int* in_sizes, int n_in,
                              void* d_out, int out_size, void* d_ws, size_t ws_size,
                              hipStream_t stream)
{
    const float* x    = (const float*)d_in[0];
    const float* y    = (const float*)d_in[1];
    const float* xpos = (const float*)d_in[2];
    const float* ypos = (const float*)d_in[3];
    const float* Wq   = (const float*)d_in[4];
    const float* bq   = (const float*)d_in[5];
    const float* Wk   = (const float*)d_in[6];
    const float* bk   = (const float*)d_in[7];
    const float* Wv   = (const float*)d_in[8];
    const float* bv   = (const float*)d_in[9];
    const float* Wr   = (const float*)d_in[10];
    const float* br   = (const float*)d_in[11];

    char*  ws    = (char*)d_ws;
    short* wbf   = (short*)(ws);                    // 4 x 65536 bf16 packed (512 KB)
    short* ctxT  = (short*)(ws + 524288);           // 32*1024 bf16 (64 KB)
    float* parts = (float*)(ws + (1 << 20));        // 512*1056 f32 (~2.2 MB)
    short* e_buf = (short*)(ws + ((size_t)4 << 20)); // 65536*256 bf16 (33.5 MB)
    short* v_buf = e_buf + (size_t)65536 * 256;      // 33.5 MB
    float* outp  = (float*)d_out;

    hipLaunchKernelGGL(wcvt_kernel, dim3(128), dim3(256), 0, stream,
                       Wq, Wk, Wv, Wr, wbf);
    hipLaunchKernelGGL(kv_kernel, dim3(2048), dim3(256), 0, stream,
                       y, ypos, wbf + 65536, wbf + 131072, bk, bv, e_buf, v_buf);
    hipLaunchKernelGGL(ctx_kernel, dim3(16, 32), dim3(256), 0, stream,
                       e_buf, v_buf, parts);
    hipLaunchKernelGGL(ctx_reduce_kernel, dim3(32), dim3(256), 0, stream,
                       parts, ctxT);
    hipLaunchKernelGGL(qout_kernel, dim3(2048), dim3(256), 0, stream,
                       x, xpos, wbf, bq, ctxT, wbf + 196608, br, outp);
}

// Round 11
// 168.558 us; speedup vs baseline: 1.5049x; 1.0032x over previous
//
#include <hip/hip_runtime.h>

// Efficient (linear) attention, fused MFMA implementation for gfx950.  v7-r10
// B=4, NX=NY=16384, C=256, H=8, dk=dv=32.  M = B*N = 65536 rows.
// R5 change (kv+qout): force load-latency hiding via ILP. All staging loads
// issued into registers before converting (16 outstanding); B-operand stream
// double-buffered (prefetch tile nf+1 while MFMAing nf). launch_bounds relaxed
// to let the compiler hold the in-flight registers.

typedef float f32x4 __attribute__((ext_vector_type(4)));
typedef short s16x4 __attribute__((ext_vector_type(4)));
typedef short s16x8 __attribute__((ext_vector_type(8)));

#define MFMA16(A, B, C) __builtin_amdgcn_mfma_f32_16x16x32_bf16((A), (B), (C), 0, 0, 0)

__device__ __forceinline__ short f2bf(float f) {
    unsigned u = __builtin_bit_cast(unsigned, f);
    u = (u + 0x7FFFu + ((u >> 16) & 1u)) >> 16;   // RNE
    return (short)u;
}
__device__ __forceinline__ float bf2f(short b) {
    unsigned u = ((unsigned)(unsigned short)b) << 16;
    return __builtin_bit_cast(float, u);
}

// ---------------------------------------------------------------------------
// K0: convert 4 weight matrices to bf16 in MFMA-fragment-packed order.
// packed[m][tile][ks][lane][8] ; element = W[tile*16 + (lane&15)][ks*32 + (lane>>4)*8 + j]
// ---------------------------------------------------------------------------
__global__ __launch_bounds__(256) void wcvt_kernel(
    const float* __restrict__ wq, const float* __restrict__ wk,
    const float* __restrict__ wv, const float* __restrict__ wr,
    short* __restrict__ wbf)
{
    int id = blockIdx.x * 256 + threadIdx.x;     // grid 128 -> 32768 frag-slots
    int m = id >> 13;                            // matrix
    int slot = id & 8191;                        // tile(4b) ks(3b) lane(6b)
    int tile = slot >> 9;
    int ks   = (slot >> 6) & 7;
    int lane = slot & 63;
    int lrow = lane & 15, lgrp = lane >> 4;
    const float* src = (m == 0) ? wq : (m == 1) ? wk : (m == 2) ? wv : wr;
    const float* p = src + (size_t)(tile * 16 + lrow) * 256 + ks * 32 + lgrp * 8;
    f32x4 a = *(const f32x4*)p;
    f32x4 b = *(const f32x4*)(p + 4);
    s16x8 o;
    o[0]=f2bf(a[0]); o[1]=f2bf(a[1]); o[2]=f2bf(a[2]); o[3]=f2bf(a[3]);
    o[4]=f2bf(b[0]); o[5]=f2bf(b[1]); o[6]=f2bf(b[2]); o[7]=f2bf(b[3]);
    *(s16x8*)(wbf + (size_t)id * 8) = o;
}

// ---------------------------------------------------------------------------
// K1: e = exp((y+ypos) @ Wk^T + bk), v = y @ Wv^T + bv   -> bf16 buffers
// 256 thr (4 waves), 32-row tile, grid 2048, 32KB LDS.
// ILP form: stage-loads fully hoisted; B double-buffered 8-deep.
// ---------------------------------------------------------------------------
__global__ __launch_bounds__(256) void kv_kernel(
    const float* __restrict__ y, const float* __restrict__ ypos,
    const short* __restrict__ wkp, const short* __restrict__ wvp,
    const float* __restrict__ bk, const float* __restrict__ bv,
    short* __restrict__ e_buf, short* __restrict__ v_buf)
{
    __shared__ short smem[32 * 512];             // 32KB, dual-purpose
    short* ak = smem;                            // [32][256] swizzled bf16(y+ypos)
    short* av = smem + 32 * 256;                 // [32][256] swizzled bf16(y)
    const int row0 = blockIdx.x * 32;
    const int t = threadIdx.x;
    const int w = t >> 6, lane = t & 63;

    { // Phase 1a: issue ALL 16 staging loads (kept in flight together)
        f32x4 ly[8], lp[8];
        #pragma unroll
        for (int it = 0; it < 8; ++it) {
            int r = it * 4 + w;
            ly[it] = *(const f32x4*)(y    + (size_t)(row0 + r) * 256 + lane * 4);
            lp[it] = *(const f32x4*)(ypos + (size_t)(row0 + r) * 256 + lane * 4);
        }
        // Phase 1b: convert + LDS write
        #pragma unroll
        for (int it = 0; it < 8; ++it) {
            int r = it * 4 + w;
            f32x4 a = ly[it];
            f32x4 k = a + lp[it];
            s16x4 ov, ok;
            ov[0]=f2bf(a[0]); ov[1]=f2bf(a[1]); ov[2]=f2bf(a[2]); ov[3]=f2bf(a[3]);
            ok[0]=f2bf(k[0]); ok[1]=f2bf(k[1]); ok[2]=f2bf(k[2]); ok[3]=f2bf(k[3]);
            int swz = ((lane >> 1) ^ (r & 7)) * 8 + (lane & 1) * 4;
            *(s16x4*)(av + r * 256 + swz) = ov;
            *(s16x4*)(ak + r * 256 + swz) = ok;
        }
    }
    __syncthreads();

    const int lrow = lane & 15, lgrp = lane >> 4;
    const bool is_k = (w < 2);                   // wave-uniform
    const int colbase = (w & 1) * 128;
    const int tile0 = colbase >> 4;
    const short* WP = is_k ? wkp : wvp;          // packed
    const float* bp = is_k ? bk : bv;
    const short* A = is_k ? ak : av;

    float bias[8];
    #pragma unroll
    for (int nf = 0; nf < 8; ++nf) bias[nf] = bp[colbase + nf * 16 + lrow];

    // A-frags from LDS into registers: af[mf][ks]
    s16x8 af[2][8];
    #pragma unroll
    for (int mf = 0; mf < 2; ++mf) {
        int rr = mf * 16 + lrow;
        #pragma unroll
        for (int ks = 0; ks < 8; ++ks) {
            int cs = ((ks * 4 + lgrp) ^ (rr & 7));
            af[mf][ks] = *(const s16x8*)(A + rr * 256 + cs * 8);
        }
    }
    __syncthreads();   // all waves have A in regs; smem reusable for C

    const short* wt = WP + lane * 8;
    s16x8 bf[2][8];
    #pragma unroll
    for (int k = 0; k < 8; ++k)                  // preload tile0
        bf[0][k] = *(const s16x8*)(wt + ((size_t)tile0 * 8 + k) * 512);

    #pragma unroll
    for (int nf = 0; nf < 8; ++nf) {
        const int cur = nf & 1, nxt = cur ^ 1;
        if (nf < 7) {                            // prefetch next tile's 8 frags
            #pragma unroll
            for (int k = 0; k < 8; ++k)
                bf[nxt][k] = *(const s16x8*)(wt + ((size_t)(tile0 + nf + 1) * 8 + k) * 512);
        }
        f32x4 a0 = (f32x4){0.f, 0.f, 0.f, 0.f};
        f32x4 a1 = (f32x4){0.f, 0.f, 0.f, 0.f};
        #pragma unroll
        for (int k = 0; k < 8; ++k) {
            a0 = MFMA16(af[0][k], bf[cur][k], a0);
            a1 = MFMA16(af[1][k], bf[cur][k], a1);
        }
        // C -> LDS [32][512] bf16, 16B-chunk XOR swizzle
        const int colp = (is_k ? 0 : 256) + colbase + nf * 16 + lrow;  // 0..511
        #pragma unroll
        for (int rr = 0; rr < 4; ++rr) {
            float v0 = a0[rr] + bias[nf];
            float v1 = a1[rr] + bias[nf];
            if (is_k) { v0 = __expf(v0); v1 = __expf(v1); }
            int lr0 = lgrp * 4 + rr;
            int lr1 = lr0 + 16;
            smem[lr0 * 512 + (((colp >> 3) ^ (lr0 & 7)) * 8) + (colp & 7)] = f2bf(v0);
            smem[lr1 * 512 + (((colp >> 3) ^ (lr1 & 7)) * 8) + (colp & 7)] = f2bf(v1);
        }
    }
    __syncthreads();

    { // coalesced store-out: iter i -> row i*4+w; lane chunk = lane^(r&7)
        #pragma unroll
        for (int i = 0; i < 8; ++i) {
            int r = i * 4 + w;
            int grow = row0 + r;
            s16x8 val = *(const s16x8*)(smem + r * 512 + (lane ^ (r & 7)) * 8);
            if (lane < 32)
                *(s16x8*)(e_buf + (size_t)grow * 256 + lane * 8) = val;
            else
                *(s16x8*)(v_buf + (size_t)grow * 256 + (lane - 32) * 8) = val;
        }
    }
}

// ---------------------------------------------------------------------------
// K2: ctx partials.  grid (16 chunks, 32 bh).  block 256 thr.  (unchanged)
// ---------------------------------------------------------------------------
__global__ __launch_bounds__(256) void ctx_kernel(
    const short* __restrict__ e_buf, const short* __restrict__ v_buf,
    float* __restrict__ partials)
{
    __shared__ float se[128 * 32];
    __shared__ float sv[128 * 32];
    __shared__ float red[4 * 1056];
    const int cb = blockIdx.x, bh = blockIdx.y;
    const int b = bh >> 3, h = bh & 7;
    const int tok0 = b * 16384 + cb * 1024;
    const int t = threadIdx.x, w = t >> 6, lane = t & 63;
    const int ckb = (lane >> 3) * 4, cvb = (lane & 7) * 4;

    f32x4 acc[4];
    #pragma unroll
    for (int i = 0; i < 4; ++i) acc[i] = (f32x4){0.f, 0.f, 0.f, 0.f};
    f32x4 dn = (f32x4){0.f, 0.f, 0.f, 0.f};

    for (int it = 0; it < 8; ++it) {
        __syncthreads();
        #pragma unroll
        for (int s = 0; s < 2; ++s) {
            int id = t + s * 256;
            int rr = id >> 2, pp = id & 3;
            size_t g = (size_t)(tok0 + it * 128 + rr) * 256 + h * 32 + pp * 8;
            s16x8 ee = *(const s16x8*)(e_buf + g);
            s16x8 vv = *(const s16x8*)(v_buf + g);
            f32x4 e0 = {bf2f(ee[0]), bf2f(ee[1]), bf2f(ee[2]), bf2f(ee[3])};
            f32x4 e1 = {bf2f(ee[4]), bf2f(ee[5]), bf2f(ee[6]), bf2f(ee[7])};
            f32x4 v0 = {bf2f(vv[0]), bf2f(vv[1]), bf2f(vv[2]), bf2f(vv[3])};
            f32x4 v1 = {bf2f(vv[4]), bf2f(vv[5]), bf2f(vv[6]), bf2f(vv[7])};
            *(f32x4*)(se + rr * 32 + pp * 8)     = e0;
            *(f32x4*)(se + rr * 32 + pp * 8 + 4) = e1;
            *(f32x4*)(sv + rr * 32 + pp * 8)     = v0;
            *(f32x4*)(sv + rr * 32 + pp * 8 + 4) = v1;
        }
        __syncthreads();
        const int r0 = w * 32;
        #pragma unroll 8
        for (int rr = 0; rr < 32; ++rr) {
            f32x4 e4 = *(const f32x4*)(se + (r0 + rr) * 32 + ckb);
            f32x4 v4 = *(const f32x4*)(sv + (r0 + rr) * 32 + cvb);
            acc[0] += e4[0] * v4;
            acc[1] += e4[1] * v4;
            acc[2] += e4[2] * v4;
            acc[3] += e4[3] * v4;
            dn += e4;
        }
    }
    __syncthreads();
    #pragma unroll
    for (int i = 0; i < 4; ++i)
        *(f32x4*)(red + w * 1056 + (ckb + i) * 32 + cvb) = acc[i];
    if ((lane & 7) == 0)
        *(f32x4*)(red + w * 1056 + 1024 + ckb) = dn;
    __syncthreads();
    float* outp = partials + (size_t)(bh * 16 + cb) * 1056;
    for (int e = t; e < 1056; e += 256)
        outp[e] = red[e] + red[1056 + e] + red[2112 + e] + red[3168 + e];
}

// K2b: reduce 16 chunks, normalize, write ctx^T bf16 [bh][cv][ck]  (unchanged)
__global__ __launch_bounds__(256) void ctx_reduce_kernel(
    const float* __restrict__ partials, short* __restrict__ ctxT)
{
    __shared__ float s[1056];
    const int bh = blockIdx.x, t = threadIdx.x;
    for (int e = t; e < 1056; e += 256) {
        float a = 0.f;
        for (int c = 0; c < 16; ++c) a += partials[(size_t)(bh * 16 + c) * 1056 + e];
        s[e] = a;
    }
    __syncthreads();
    for (int e = t; e < 1024; e += 256) {
        int ck = e >> 5, cv = e & 31;
        float val = s[e] / s[1024 + ck];
        ctxT[(size_t)bh * 1024 + cv * 32 + ck] = f2bf(val);
    }
}

// ---------------------------------------------------------------------------
// K3: fused q pass.  256 thr, 32 rows, grid 2048.  ILP form: hoisted staging
// loads + double-buffered B in both GEMM loops.
// ---------------------------------------------------------------------------
__global__ __launch_bounds__(256) void qout_kernel(
    const float* __restrict__ x, const float* __restrict__ xpos,
    const short* __restrict__ wqp, const float* __restrict__ bq,
    const short* __restrict__ ctxT,
    const short* __restrict__ wrp, const float* __restrict__ br,
    float* __restrict__ out)
{
    __shared__ short alds[32 * 256];             // x-tile, then attended (swizzled)
    __shared__ short qlds[4][32 * 64];           // per-wave softmaxed q (swizzled)
    const int row0 = blockIdx.x * 32;
    const int b = row0 >> 14;
    const int t = threadIdx.x;
    const int w = t >> 6, lane = t & 63;

    { // stage bf16(x+xpos): all 16 loads in flight, then convert
        f32x4 lx[8], lp[8];
        #pragma unroll
        for (int it = 0; it < 8; ++it) {
            int r = it * 4 + w;
            lx[it] = *(const f32x4*)(x    + (size_t)(row0 + r) * 256 + lane * 4);
            lp[it] = *(const f32x4*)(xpos + (size_t)(row0 + r) * 256 + lane * 4);
        }
        #pragma unroll
        for (int it = 0; it < 8; ++it) {
            int r = it * 4 + w;
            f32x4 a = lx[it] + lp[it];
            s16x4 o;
            o[0]=f2bf(a[0]); o[1]=f2bf(a[1]); o[2]=f2bf(a[2]); o[3]=f2bf(a[3]);
            int swz = ((lane >> 1) ^ (r & 7)) * 8 + (lane & 1) * 4;
            *(s16x4*)(alds + r * 256 + swz) = o;
        }
    }
    __syncthreads();

    const int lrow = lane & 15, lgrp = lane >> 4;
    const int wc = w * 64;                        // wave owns cols [wc, wc+64)
    const int tile0 = wc >> 4;

    float biasq[4];
    #pragma unroll
    for (int nf = 0; nf < 4; ++nf) biasq[nf] = bq[wc + nf * 16 + lrow];

    f32x4 acc[2][4];
    #pragma unroll
    for (int mf = 0; mf < 2; ++mf)
        #pragma unroll
        for (int nf = 0; nf < 4; ++nf) acc[mf][nf] = (f32x4){0.f, 0.f, 0.f, 0.f};

    {   // q-GEMM with double-buffered B (4 frags per ks step)
        const short* wq8 = wqp + lane * 8;
        s16x8 bfq[2][4];
        #pragma unroll
        for (int nf = 0; nf < 4; ++nf)
            bfq[0][nf] = *(const s16x8*)(wq8 + ((size_t)(tile0 + nf) * 8 + 0) * 512);
        #pragma unroll
        for (int ks = 0; ks < 8; ++ks) {
            const int cur = ks & 1, nxt = cur ^ 1;
            if (ks < 7) {
                #pragma unroll
                for (int nf = 0; nf < 4; ++nf)
                    bfq[nxt][nf] = *(const s16x8*)(wq8 + ((size_t)(tile0 + nf) * 8 + ks + 1) * 512);
            }
            s16x8 af[2];
            #pragma unroll
            for (int mf = 0; mf < 2; ++mf) {
                int rr = mf * 16 + lrow;
                int cs = (ks * 4 + lgrp) ^ (rr & 7);
                af[mf] = *(const s16x8*)(alds + rr * 256 + cs * 8);
            }
            #pragma unroll
            for (int nf = 0; nf < 4; ++nf) {
                acc[0][nf] = MFMA16(af[0], bfq[cur][nf], acc[0][nf]);
                acc[1][nf] = MFMA16(af[1], bfq[cur][nf], acc[1][nf]);
            }
        }
    }

    // per-head softmax over 32 channels (no max-sub needed; |q| < ~4)
    short* ql = (short*)qlds[w];
    #pragma unroll
    for (int mf = 0; mf < 2; ++mf) {
        f32x4 e[4];
        #pragma unroll
        for (int nf = 0; nf < 4; ++nf)
            #pragma unroll
            for (int rr = 0; rr < 4; ++rr)
                e[nf][rr] = __expf(acc[mf][nf][rr] + biasq[nf]);
        #pragma unroll
        for (int hl = 0; hl < 2; ++hl) {
            #pragma unroll
            for (int rr = 0; rr < 4; ++rr) {
                float s = e[hl * 2][rr] + e[hl * 2 + 1][rr];
                s += __shfl_xor(s, 1);
                s += __shfl_xor(s, 2);
                s += __shfl_xor(s, 4);
                s += __shfl_xor(s, 8);
                float rinv = 1.0f / s;
                int row = mf * 16 + lgrp * 4 + rr;
                #pragma unroll
                for (int n2 = 0; n2 < 2; ++n2) {
                    int colc = hl * 32 + n2 * 16 + lrow;
                    int cs = (colc >> 3) ^ (row & 7);
                    ql[row * 64 + cs * 8 + (colc & 7)] = f2bf(e[hl * 2 + n2][rr] * rinv);
                }
            }
        }
    }
    __syncthreads();

    // attend: att[32 x 64] = qsm @ ctx (per head)
    f32x4 att[2][2][2];
    #pragma unroll
    for (int hl = 0; hl < 2; ++hl)
        #pragma unroll
        for (int mf = 0; mf < 2; ++mf)
            #pragma unroll
            for (int n2 = 0; n2 < 2; ++n2) att[hl][mf][n2] = (f32x4){0.f,0.f,0.f,0.f};

    #pragma unroll
    for (int hl = 0; hl < 2; ++hl) {
        const short* cbase = ctxT + (size_t)(b * 8 + w * 2 + hl) * 1024;
        s16x8 bctx[2];
        #pragma unroll
        for (int n2 = 0; n2 < 2; ++n2)
            bctx[n2] = *(const s16x8*)(cbase + (n2 * 16 + lrow) * 32 + lgrp * 8);
        #pragma unroll
        for (int mf = 0; mf < 2; ++mf) {
            int row = mf * 16 + lrow;
            int cs = (hl * 4 + lgrp) ^ (row & 7);
            s16x8 aq = *(const s16x8*)(ql + row * 64 + cs * 8);
            #pragma unroll
            for (int n2 = 0; n2 < 2; ++n2)
                att[hl][mf][n2] = MFMA16(aq, bctx[n2], att[hl][mf][n2]);
        }
    }

    // attended -> alds (bf16, swizzled)
    #pragma unroll
    for (int hl = 0; hl < 2; ++hl)
      #pragma unroll
      for (int mf = 0; mf < 2; ++mf)
        #pragma unroll
        for (int n2 = 0; n2 < 2; ++n2)
          #pragma unroll
          for (int rr = 0; rr < 4; ++rr) {
              int row = mf * 16 + lgrp * 4 + rr;
              int col = wc + hl * 32 + n2 * 16 + lrow;
              int cs = (col >> 3) ^ (row & 7);
              alds[row * 256 + cs * 8 + (col & 7)] = f2bf(att[hl][mf][n2][rr]);
          }
    __syncthreads();

    // reprojection: out = attended @ Wr^T + br  (double-buffered B)
    float biasr[4];
    #pragma unroll
    for (int nf = 0; nf < 4; ++nf) biasr[nf] = br[wc + nf * 16 + lrow];

    f32x4 acc2[2][4];
    #pragma unroll
    for (int mf = 0; mf < 2; ++mf)
        #pragma unroll
        for (int nf = 0; nf < 4; ++nf) acc2[mf][nf] = (f32x4){0.f, 0.f, 0.f, 0.f};

    {
        const short* wr8 = wrp + lane * 8;
        s16x8 bfr[2][4];
        #pragma unroll
        for (int nf = 0; nf < 4; ++nf)
            bfr[0][nf] = *(const s16x8*)(wr8 + ((size_t)(tile0 + nf) * 8 + 0) * 512);
        #pragma unroll
        for (int ks = 0; ks < 8; ++ks) {
            const int cur = ks & 1, nxt = cur ^ 1;
            if (ks < 7) {
                #pragma unroll
                for (int nf = 0; nf < 4; ++nf)
                    bfr[nxt][nf] = *(const s16x8*)(wr8 + ((size_t)(tile0 + nf) * 8 + ks + 1) * 512);
            }
            s16x8 af[2];
            #pragma unroll
            for (int mf = 0; mf < 2; ++mf) {
                int rr = mf * 16 + lrow;
                int cs = (ks * 4 + lgrp) ^ (rr & 7);
                af[mf] = *(const s16x8*)(alds + rr * 256 + cs * 8);
            }
            #pragma unroll
            for (int nf = 0; nf < 4; ++nf) {
                acc2[0][nf] = MFMA16(af[0], bfr[cur][nf], acc2[0][nf]);
                acc2[1][nf] = MFMA16(af[1], bfr[cur][nf], acc2[1][nf]);
            }
        }
    }

    #pragma unroll
    for (int mf = 0; mf < 2; ++mf)
      #pragma unroll
      for (int nf = 0; nf < 4; ++nf)
        #pragma unroll
        for (int rr = 0; rr < 4; ++rr) {
            int grow = row0 + mf * 16 + lgrp * 4 + rr;
            out[(size_t)grow * 256 + wc + nf * 16 + lrow] = acc2[mf][nf][rr] + biasr[nf];
        }
}

// ---------------------------------------------------------------------------
extern "C" void kernel_launch(void* const* d_in, const int* in_sizes, int n_in,
                              void* d_out, int out_size, void* d_ws, size_t ws_size,
                              hipStream_t stream)
{
    const float* x    = (const float*)d_in[0];
    const float* y    = (const float*)d_in[1];
    const float* xpos = (const float*)d_in[2];
    const float* ypos = (const float*)d_in[3];
    const float* Wq   = (const float*)d_in[4];
    const float* bq   = (const float*)d_in[5];
    const float* Wk   = (const float*)d_in[6];
    const float* bk   = (const float*)d_in[7];
    const float* Wv   = (const float*)d_in[8];
    const float* bv   = (const float*)d_in[9];
    const float* Wr   = (const float*)d_in[10];
    const float* br   = (const float*)d_in[11];

    char*  ws    = (char*)d_ws;
    short* wbf   = (short*)(ws);                    // 4 x 65536 bf16 packed (512 KB)
    short* ctxT  = (short*)(ws + 524288);           // 32*1024 bf16 (64 KB)
    float* parts = (float*)(ws + (1 << 20));        // 512*1056 f32 (~2.2 MB)
    short* e_buf = (short*)(ws + ((size_t)4 << 20)); // 65536*256 bf16 (33.5 MB)
    short* v_buf = e_buf + (size_t)65536 * 256;      // 33.5 MB
    float* outp  = (float*)d_out;

    hipLaunchKernelGGL(wcvt_kernel, dim3(128), dim3(256), 0, stream,
                       Wq, Wk, Wv, Wr, wbf);
    hipLaunchKernelGGL(kv_kernel, dim3(2048), dim3(256), 0, stream,
                       y, ypos, wbf + 65536, wbf + 131072, bk, bv, e_buf, v_buf);
    hipLaunchKernelGGL(ctx_kernel, dim3(16, 32), dim3(256), 0, stream,
                       e_buf, v_buf, parts);
    hipLaunchKernelGGL(ctx_reduce_kernel, dim3(32), dim3(256), 0, stream,
                       parts, ctxT);
    hipLaunchKernelGGL(qout_kernel, dim3(2048), dim3(256), 0, stream,
                       x, xpos, wbf, bq, ctxT, wbf + 196608, br, outp);
}